// Round 5
// baseline (383.833 us; speedup 1.0000x reference)
//
#include <hip/hip_runtime.h>
#include <math.h>

#define N_NODES 20000
#define N_EDGES 640000
#define HID 128
#define NPAD 20224

typedef __attribute__((ext_vector_type(8))) short bf16x8;
typedef __attribute__((ext_vector_type(4))) float f32x4;

#define FIX_SCALE 274877906944.0   // 2^38
#define FIX_MASK ((1ull << 48) - 1)

__device__ inline short f2bf(float f) {
    unsigned u = __builtin_bit_cast(unsigned, f);
    u += 0x7fffu + ((u >> 16) & 1u);      // RNE
    return (short)(u >> 16);
}
__device__ inline float bf2f(short s) {
    unsigned u = ((unsigned)(unsigned short)s) << 16;
    return __builtin_bit_cast(float, u);
}
__device__ inline float4 unpack_bf4(uint2 v) {
    float4 f;
    f.x = __builtin_bit_cast(float, v.x << 16);
    f.y = __builtin_bit_cast(float, v.x & 0xffff0000u);
    f.z = __builtin_bit_cast(float, v.y << 16);
    f.w = __builtin_bit_cast(float, v.y & 0xffff0000u);
    return f;
}
__device__ inline uint2 pack_bf4(float4 f) {
    uint2 v;
    v.x = (unsigned)(unsigned short)f2bf(f.x) | ((unsigned)(unsigned short)f2bf(f.y) << 16);
    v.y = (unsigned)(unsigned short)f2bf(f.z) | ((unsigned)(unsigned short)f2bf(f.w) << 16);
    return v;
}

// ---------- CSR build (4-sharded histogram to cut atomic contention) ----------
__global__ __launch_bounds__(256) void k_init(unsigned long long* packed) {
    int i = blockIdx.x * 256 + threadIdx.x;
    if (i < 4 * NPAD) packed[i] = 0ull;
}

// one u64 atomic per edge into shard (blockIdx&3): count [63:48], fixed-point deg [47:0]
__global__ __launch_bounds__(256) void k_hist(unsigned long long* packed, int* __restrict__ rank,
                                              const int* __restrict__ dst,
                                              const float* __restrict__ ew) {
    int e = blockIdx.x * 256 + threadIdx.x;
    int shard = blockIdx.x & 3;
    if (e < N_EDGES) {
        int d = dst[e];
        unsigned long long add = (1ull << 48) | (unsigned long long)((double)ew[e] * FIX_SCALE);
        unsigned long long old = atomicAdd(&packed[shard * NPAD + d], add);
        rank[e] = (int)(old >> 48);
    }
}

__global__ __launch_bounds__(256) void k_dinv(const unsigned long long* __restrict__ packed,
                                              float* __restrict__ dinv) {
    int i = blockIdx.x * 256 + threadIdx.x;
    if (i < N_NODES) {
        double deg = 1.0;   // self-loop
#pragma unroll
        for (int s = 0; s < 4; s++)
            deg += (double)(packed[s * NPAD + i] & FIX_MASK) * (1.0 / FIX_SCALE);
        dinv[i] = rsqrtf((float)deg);
    }
}

// block scan of per-node totals -> rp; also per-shard slot bases sb[s][i]
__global__ __launch_bounds__(1024) void k_scan(const unsigned long long* __restrict__ packed,
                                               int* __restrict__ rp, int* __restrict__ sb) {
    __shared__ int smem[1024];
    int tid = threadIdx.x;
    int base = tid * 20;
    int loc[20];
    int run = 0;
#pragma unroll
    for (int j = 0; j < 20; j++) {
        int i = base + j;
        int tot = 0;
        if (i < N_NODES) {
#pragma unroll
            for (int s = 0; s < 4; s++) tot += (int)(packed[s * NPAD + i] >> 48);
        }
        loc[j] = run; run += tot;
    }
    smem[tid] = run;
    __syncthreads();
    for (int off = 1; off < 1024; off <<= 1) {
        int t = (tid >= off) ? smem[tid - off] : 0;
        __syncthreads();
        smem[tid] += t;
        __syncthreads();
    }
    int excl = smem[tid] - run;
#pragma unroll
    for (int j = 0; j < 20; j++) {
        int i = base + j;
        if (i < N_NODES) {
            int e = excl + loc[j];
            rp[i] = e;
            int acc = e;
#pragma unroll
            for (int s = 0; s < 4; s++) {
                sb[s * NPAD + i] = acc;
                acc += (int)(packed[s * NPAD + i] >> 48);
            }
        }
    }
    if (tid == 1023) rp[N_NODES] = smem[1023];
}

// atomic-free fill: slot = sb[shard][dst] + rank
__global__ __launch_bounds__(256) void k_fill(const int* __restrict__ src,
                                              const int* __restrict__ dst,
                                              const float* __restrict__ ew,
                                              const float* __restrict__ dinv,
                                              const int* __restrict__ sb,
                                              const int* __restrict__ rank,
                                              int2* __restrict__ csr) {
    int e = blockIdx.x * 256 + threadIdx.x;
    int shard = blockIdx.x & 3;
    if (e < N_EDGES) {
        int s = src[e], d = dst[e];
        int slot = sb[shard * NPAD + d] + rank[e];
        float w = dinv[s] * ew[e] * dinv[d];
        csr[slot] = make_int2(s, __builtin_bit_cast(int, w));
    }
}

// ---------- fp32 -> bf16 conversions ----------
__global__ __launch_bounds__(256) void k_cvt2(const float* __restrict__ x, const float* __restrict__ h,
                                              short* __restrict__ xb, short* __restrict__ hb) {
    const int NH4 = (N_NODES * HID) / 4;
    int i = blockIdx.x * 256 + threadIdx.x;
    const float* s; short* d; int idx;
    if (i < NH4) { s = x; d = xb; idx = i; } else { s = h; d = hb; idx = i - NH4; }
    float4 v = ((const float4*)s)[idx];
    short4 o;
    o.x = f2bf(v.x); o.y = f2bf(v.y); o.z = f2bf(v.z); o.w = f2bf(v.w);
    ((short4*)d)[idx] = o;
}

// transpose + convert the 5 weights: WT[n][k] = bf16(W[k][n])
__global__ __launch_bounds__(256) void k_wcvt(const float* __restrict__ W1, const float* __restrict__ W2,
                                              const float* __restrict__ Wu, const float* __restrict__ Wr,
                                              const float* __restrict__ Wc,
                                              short* WT1, short* WT2, short* WTu, short* WTr, short* WTc) {
    int i = blockIdx.x * 256 + threadIdx.x;   // 0..131071
    if (i < 32768) {
        const float* W = (i < 16384) ? W1 : W2;
        short* T = (i < 16384) ? WT1 : WT2;
        int j = i & 16383;
        int n = j >> 7, k = j & 127;
        T[n * 128 + k] = f2bf(W[k * 128 + n]);
    } else {
        int j = i - 32768;
        const float* W = Wu; short* T = WTu;
        if (j >= 65536)      { W = Wc; T = WTc; j -= 65536; }
        else if (j >= 32768) { W = Wr; T = WTr; j -= 32768; }
        int n = j >> 8, k = j & 255;
        T[n * 256 + k] = f2bf(W[k * 128 + n]);
    }
}

// ---------- MFMA GEMM: 16 rows/block (1250 blocks), waves split output cols ----------
__global__ __launch_bounds__(256) void k_gemm_mfma(const short* __restrict__ Ab,
                                                   const short* __restrict__ WT,
                                                   short* __restrict__ Cb) {
    __shared__ short As[16 * 136];
    int tid = threadIdx.x;
    int r0 = blockIdx.x * 16;
    {   // stage 16 rows x 128 cols: 256 bf16x8 chunks, one per thread
        int row = tid >> 4;
        int col0 = (tid & 15) * 8;
        *(bf16x8*)(&As[row * 136 + col0]) = *(const bf16x8*)(Ab + (size_t)(r0 + row) * HID + col0);
    }
    __syncthreads();
    int wave = tid >> 6, lane = tid & 63;
    int m = lane & 15, quad = lane >> 4;
    f32x4 acc[2];
    acc[0] = (f32x4){0.f, 0.f, 0.f, 0.f};
    acc[1] = acc[0];
#pragma unroll
    for (int ks = 0; ks < 4; ks++) {
        int k0 = ks * 32 + quad * 8;
        bf16x8 a = *(const bf16x8*)(&As[m * 136 + k0]);
#pragma unroll
        for (int j = 0; j < 2; j++) {
            int n = (wave * 2 + j) * 16 + m;
            bf16x8 b = *(const bf16x8*)(WT + n * 128 + k0);
            acc[j] = __builtin_amdgcn_mfma_f32_16x16x32_bf16(a, b, acc[j], 0, 0, 0);
        }
    }
#pragma unroll
    for (int j = 0; j < 2; j++) {
        int col = (wave * 2 + j) * 16 + m;
#pragma unroll
        for (int rg = 0; rg < 4; rg++) {
            int grow = r0 + quad * 4 + rg;
            Cb[(size_t)grow * HID + col] = f2bf(acc[j][rg]);
        }
    }
}

// ---------- gather aggregation: one wave per dst node, half-wave per edge pair ----------
__global__ __launch_bounds__(256) void k_aggregate(const short* __restrict__ xw,
                                                   short* __restrict__ outb,
                                                   const int* __restrict__ rp,
                                                   const int2* __restrict__ csr,
                                                   const float* __restrict__ dinv,
                                                   const float* __restrict__ bias,
                                                   int act) {
    int node = blockIdx.x * 4 + (threadIdx.x >> 6);
    int lane = threadIdx.x & 63;
    int half = lane >> 5;
    int l = lane & 31;
    float4 acc = {0.f, 0.f, 0.f, 0.f};
    if (half == 0) {   // self-loop term, counted once
        float dv = dinv[node];
        float dv2 = dv * dv;
        float4 v = unpack_bf4(((const uint2*)(xw + (size_t)node * HID))[l]);
        acc.x = v.x * dv2; acc.y = v.y * dv2; acc.z = v.z * dv2; acc.w = v.w * dv2;
    }
    int j = rp[node], end = rp[node + 1];
    for (; j + 7 < end; j += 8) {
        int2 e0 = csr[j + 0 + half];
        int2 e1 = csr[j + 2 + half];
        int2 e2 = csr[j + 4 + half];
        int2 e3 = csr[j + 6 + half];
        float4 v0 = unpack_bf4(((const uint2*)(xw + (size_t)e0.x * HID))[l]);
        float4 v1 = unpack_bf4(((const uint2*)(xw + (size_t)e1.x * HID))[l]);
        float4 v2 = unpack_bf4(((const uint2*)(xw + (size_t)e2.x * HID))[l]);
        float4 v3 = unpack_bf4(((const uint2*)(xw + (size_t)e3.x * HID))[l]);
        float w0 = __builtin_bit_cast(float, e0.y);
        float w1 = __builtin_bit_cast(float, e1.y);
        float w2 = __builtin_bit_cast(float, e2.y);
        float w3 = __builtin_bit_cast(float, e3.y);
        acc.x += v0.x * w0; acc.y += v0.y * w0; acc.z += v0.z * w0; acc.w += v0.w * w0;
        acc.x += v1.x * w1; acc.y += v1.y * w1; acc.z += v1.z * w1; acc.w += v1.w * w1;
        acc.x += v2.x * w2; acc.y += v2.y * w2; acc.z += v2.z * w2; acc.w += v2.w * w2;
        acc.x += v3.x * w3; acc.y += v3.y * w3; acc.z += v3.z * w3; acc.w += v3.w * w3;
    }
    for (; j + 1 < end; j += 2) {
        int2 e0 = csr[j + half];
        float4 v0 = unpack_bf4(((const uint2*)(xw + (size_t)e0.x * HID))[l]);
        float w0 = __builtin_bit_cast(float, e0.y);
        acc.x += v0.x * w0; acc.y += v0.y * w0; acc.z += v0.z * w0; acc.w += v0.w * w0;
    }
    if (j < end && half == 0) {
        int2 e0 = csr[j];
        float4 v0 = unpack_bf4(((const uint2*)(xw + (size_t)e0.x * HID))[l]);
        float w0 = __builtin_bit_cast(float, e0.y);
        acc.x += v0.x * w0; acc.y += v0.y * w0; acc.z += v0.z * w0; acc.w += v0.w * w0;
    }
    acc.x += __shfl_xor(acc.x, 32);
    acc.y += __shfl_xor(acc.y, 32);
    acc.z += __shfl_xor(acc.z, 32);
    acc.w += __shfl_xor(acc.w, 32);
    if (half == 0) {
        float4 b = ((const float4*)bias)[l];
        acc.x += b.x; acc.y += b.y; acc.z += b.z; acc.w += b.w;
        if (act == 0) {
            acc.x = fmaxf(acc.x, 0.f); acc.y = fmaxf(acc.y, 0.f);
            acc.z = fmaxf(acc.z, 0.f); acc.w = fmaxf(acc.w, 0.f);
        } else {
            acc.x = 1.f / (1.f + __expf(-acc.x)); acc.y = 1.f / (1.f + __expf(-acc.y));
            acc.z = 1.f / (1.f + __expf(-acc.z)); acc.w = 1.f / (1.f + __expf(-acc.w));
        }
        ((uint2*)(outb + (size_t)node * HID))[l] = pack_bf4(acc);
    }
}

// ---------- fused gate: 16 rows/block (1250 blocks), waves split output cols ----------
// NOTE: rows are block-shared (cols wave-split), so the in-place r*h update needs a
// barrier BEFORE writing (phase-1 a-loads of other waves read the h half) and after.
__global__ __launch_bounds__(256) void k_gate(const short* __restrict__ xgb, const short* __restrict__ hb,
                                              const float* __restrict__ hf,
                                              const short* __restrict__ WTu, const short* __restrict__ WTr,
                                              const short* __restrict__ WTc,
                                              const float* __restrict__ pbu, const float* __restrict__ pbr,
                                              const float* __restrict__ pbc,
                                              float* __restrict__ out) {
    __shared__ short Xs[16 * 264];   // [row][0:128]=xg, [128:256]=h (later r*h)
    int tid = threadIdx.x;
    int r0 = blockIdx.x * 16;
#pragma unroll
    for (int i = 0; i < 2; i++) {
        int c = tid + i * 256;       // 512 bf16x8 chunks
        int row = c >> 5;
        int col0 = (c & 31) * 8;
        int grow = r0 + row;
        bf16x8 v;
        if (col0 < 128) v = *(const bf16x8*)(xgb + (size_t)grow * HID + col0);
        else            v = *(const bf16x8*)(hb + (size_t)grow * HID + (col0 - 128));
        *(bf16x8*)(&Xs[row * 264 + col0]) = v;
    }
    __syncthreads();
    int wave = tid >> 6, lane = tid & 63;
    int m = lane & 15, quad = lane >> 4;
    f32x4 au[2], ar[2];
    au[0] = (f32x4){0.f, 0.f, 0.f, 0.f};
    au[1] = au[0]; ar[0] = au[0]; ar[1] = au[0];
#pragma unroll
    for (int ks = 0; ks < 8; ks++) {
        int k0 = ks * 32 + quad * 8;
        bf16x8 a = *(const bf16x8*)(&Xs[m * 264 + k0]);
#pragma unroll
        for (int j = 0; j < 2; j++) {
            int n = (wave * 2 + j) * 16 + m;
            bf16x8 bu_f = *(const bf16x8*)(WTu + n * 256 + k0);
            au[j] = __builtin_amdgcn_mfma_f32_16x16x32_bf16(a, bu_f, au[j], 0, 0, 0);
            bf16x8 br_f = *(const bf16x8*)(WTr + n * 256 + k0);
            ar[j] = __builtin_amdgcn_mfma_f32_16x16x32_bf16(a, br_f, ar[j], 0, 0, 0);
        }
    }
    __syncthreads();   // all phase-1 reads of the h half must complete before overwrite
#pragma unroll
    for (int j = 0; j < 2; j++) {
        int col = (wave * 2 + j) * 16 + m;
        float brv = pbr[col];
#pragma unroll
        for (int rg = 0; rg < 4; rg++) {
            int trow = quad * 4 + rg;
            float rv = 1.f / (1.f + __expf(-(ar[j][rg] + brv)));
            float hv = bf2f(Xs[trow * 264 + 128 + col]);
            Xs[trow * 264 + 128 + col] = f2bf(rv * hv);
        }
    }
    __syncthreads();
    f32x4 ac[2];
    ac[0] = (f32x4){0.f, 0.f, 0.f, 0.f};
    ac[1] = ac[0];
#pragma unroll
    for (int ks = 0; ks < 8; ks++) {
        int k0 = ks * 32 + quad * 8;
        bf16x8 a = *(const bf16x8*)(&Xs[m * 264 + k0]);
#pragma unroll
        for (int j = 0; j < 2; j++) {
            int n = (wave * 2 + j) * 16 + m;
            bf16x8 bc_f = *(const bf16x8*)(WTc + n * 256 + k0);
            ac[j] = __builtin_amdgcn_mfma_f32_16x16x32_bf16(a, bc_f, ac[j], 0, 0, 0);
        }
    }
#pragma unroll
    for (int j = 0; j < 2; j++) {
        int col = (wave * 2 + j) * 16 + m;
        float buv = pbu[col], bcv = pbc[col];
#pragma unroll
        for (int rg = 0; rg < 4; rg++) {
            int grow = r0 + quad * 4 + rg;
            float uv = 1.f / (1.f + __expf(-(au[j][rg] + buv)));
            float cv = tanhf(ac[j][rg] + bcv);
            float hv = hf[(size_t)grow * HID + col];
            out[(size_t)grow * HID + col] = uv * hv + (1.f - uv) * cv;
        }
    }
}

extern "C" void kernel_launch(void* const* d_in, const int* in_sizes, int n_in,
                              void* d_out, int out_size, void* d_ws, size_t ws_size,
                              hipStream_t stream) {
    const float* x  = (const float*)d_in[0];
    const int*   ei = (const int*)d_in[1];
    const float* ew = (const float*)d_in[2];
    const float* h  = (const float*)d_in[3];
    const float* W1 = (const float*)d_in[4];
    const float* b1 = (const float*)d_in[5];
    const float* W2 = (const float*)d_in[6];
    const float* b2 = (const float*)d_in[7];
    const float* Wu = (const float*)d_in[8];
    const float* bu = (const float*)d_in[9];
    const float* Wr = (const float*)d_in[10];
    const float* br = (const float*)d_in[11];
    const float* Wc = (const float*)d_in[12];
    const float* bc = (const float*)d_in[13];
    const int* src = ei;
    const int* dst = ei + N_EDGES;
    float* out = (float*)d_out;

    const size_t NH = (size_t)N_NODES * HID;
    float* ws = (float*)d_ws;
    float* dinv = ws;                                          // NPAD f32
    int*   rp   = (int*)(ws + NPAD);                           // NPAD
    unsigned long long* packed = (unsigned long long*)(ws + 2 * NPAD);  // 4*NPAD u64 = 8*NPAD f32
    int*   sb   = (int*)(ws + 10 * NPAD);                      // 4*NPAD
    int*   rank = (int*)(ws + 14 * NPAD);                      // N_EDGES
    int2*  csr  = (int2*)(ws + 14 * NPAD + N_EDGES);           // N_EDGES int2
    short* xb  = (short*)(ws + 14 * NPAD + 3 * N_EDGES);
    short* hb  = xb + NH;
    short* xw  = hb + NH;
    short* h1b = xw + NH;
    short* xgb = h1b + NH;
    short* WT1 = xgb + NH;
    short* WT2 = WT1 + 16384;
    short* WTu = WT2 + 16384;
    short* WTr = WTu + 32768;
    short* WTc = WTr + 32768;

    // CSR + normalization
    k_init<<<(4 * NPAD + 255) / 256, 256, 0, stream>>>(packed);
    k_hist<<<N_EDGES / 256, 256, 0, stream>>>(packed, rank, dst, ew);
    k_dinv<<<(N_NODES + 255) / 256, 256, 0, stream>>>(packed, dinv);
    k_scan<<<1, 1024, 0, stream>>>(packed, rp, sb);
    k_fill<<<N_EDGES / 256, 256, 0, stream>>>(src, dst, ew, dinv, sb, rank, csr);

    // bf16 conversions
    k_cvt2<<<(int)(2 * NH / 1024), 256, 0, stream>>>(x, h, xb, hb);
    k_wcvt<<<512, 256, 0, stream>>>(W1, W2, Wu, Wr, Wc, WT1, WT2, WTu, WTr, WTc);

    // layer 1
    k_gemm_mfma<<<N_NODES / 16, 256, 0, stream>>>(xb, WT1, xw);
    k_aggregate<<<N_NODES / 4, 256, 0, stream>>>(xw, h1b, rp, csr, dinv, b1, 0);
    // layer 2
    k_gemm_mfma<<<N_NODES / 16, 256, 0, stream>>>(h1b, WT2, xw);
    k_aggregate<<<N_NODES / 4, 256, 0, stream>>>(xw, xgb, rp, csr, dinv, b2, 1);
    // fused gating
    k_gate<<<N_NODES / 16, 256, 0, stream>>>(xgb, hb, h, WTu, WTr, WTc, bu, br, bc, out);
}

// Round 6
// 257.789 us; speedup vs baseline: 1.4889x; 1.4889x over previous
//
#include <hip/hip_runtime.h>
#include <math.h>

#define N_NODES 20000
#define N_EDGES 640000
#define HID 128
#define NPAD 20224
#define NBLK 79   // ceil(N_NODES/256)

typedef __attribute__((ext_vector_type(8))) short bf16x8;
typedef __attribute__((ext_vector_type(4))) float f32x4;

#define FIX_SCALE 274877906944.0   // 2^38
#define FIX_MASK ((1ull << 48) - 1)

__device__ inline short f2bf(float f) {
    unsigned u = __builtin_bit_cast(unsigned, f);
    u += 0x7fffu + ((u >> 16) & 1u);      // RNE
    return (short)(u >> 16);
}
__device__ inline float bf2f(short s) {
    unsigned u = ((unsigned)(unsigned short)s) << 16;
    return __builtin_bit_cast(float, u);
}
__device__ inline float4 unpack_bf4(uint2 v) {
    float4 f;
    f.x = __builtin_bit_cast(float, v.x << 16);
    f.y = __builtin_bit_cast(float, v.x & 0xffff0000u);
    f.z = __builtin_bit_cast(float, v.y << 16);
    f.w = __builtin_bit_cast(float, v.y & 0xffff0000u);
    return f;
}
__device__ inline uint2 pack_bf4(float4 f) {
    uint2 v;
    v.x = (unsigned)(unsigned short)f2bf(f.x) | ((unsigned)(unsigned short)f2bf(f.y) << 16);
    v.y = (unsigned)(unsigned short)f2bf(f.z) | ((unsigned)(unsigned short)f2bf(f.w) << 16);
    return v;
}

// ---------- CSR build (4-sharded histogram to cut atomic contention) ----------
__global__ __launch_bounds__(256) void k_init(unsigned long long* packed) {
    int i = blockIdx.x * 256 + threadIdx.x;
    if (i < 4 * NPAD) packed[i] = 0ull;
}

// one u64 atomic per edge into shard (blockIdx&3): count [63:48], fixed-point deg [47:0]
__global__ __launch_bounds__(256) void k_hist(unsigned long long* packed, int* __restrict__ rank,
                                              const int* __restrict__ dst,
                                              const float* __restrict__ ew) {
    int e = blockIdx.x * 256 + threadIdx.x;
    int shard = blockIdx.x & 3;
    if (e < N_EDGES) {
        int d = dst[e];
        unsigned long long add = (1ull << 48) | (unsigned long long)((double)ew[e] * FIX_SCALE);
        unsigned long long old = atomicAdd(&packed[shard * NPAD + d], add);
        rank[e] = (int)(old >> 48);
    }
}

// ---------- multi-block scan, phase 1: per-node totals + per-block sums ----------
__global__ __launch_bounds__(256) void k_scan_part(const unsigned long long* __restrict__ packed,
                                                   int* __restrict__ tot, int* __restrict__ bsum) {
    __shared__ int red[256];
    int tid = threadIdx.x;
    int i = blockIdx.x * 256 + tid;
    int t = 0;
    if (i < N_NODES) {
#pragma unroll
        for (int s = 0; s < 4; s++) t += (int)(packed[s * NPAD + i] >> 48);
        tot[i] = t;
    }
    red[tid] = t;
    __syncthreads();
    for (int off = 128; off > 0; off >>= 1) {
        if (tid < off) red[tid] += red[tid + off];
        __syncthreads();
    }
    if (tid == 0) bsum[blockIdx.x] = red[0];
}

// ---------- phase 2: exclusive scan of NBLK block sums (1 small block) ----------
__global__ __launch_bounds__(128) void k_scan_bsum(const int* __restrict__ bsum,
                                                   int* __restrict__ boff) {
    __shared__ int smem[128];
    int tid = threadIdx.x;
    int v = (tid < NBLK) ? bsum[tid] : 0;
    smem[tid] = v;
    __syncthreads();
    for (int off = 1; off < 128; off <<= 1) {
        int t = (tid >= off) ? smem[tid - off] : 0;
        __syncthreads();
        smem[tid] += t;
        __syncthreads();
    }
    if (tid < NBLK) boff[tid] = smem[tid] - v;   // exclusive
}

// ---------- phase 3: final scan -> rp, per-shard bases sb, and dinv ----------
__global__ __launch_bounds__(256) void k_scan_final(const unsigned long long* __restrict__ packed,
                                                    const int* __restrict__ tot,
                                                    const int* __restrict__ boff,
                                                    int* __restrict__ rp, int* __restrict__ sb,
                                                    float* __restrict__ dinv) {
    __shared__ int smem[256];
    int tid = threadIdx.x;
    int i = blockIdx.x * 256 + tid;
    int t = (i < N_NODES) ? tot[i] : 0;
    smem[tid] = t;
    __syncthreads();
    for (int off = 1; off < 256; off <<= 1) {
        int x = (tid >= off) ? smem[tid - off] : 0;
        __syncthreads();
        smem[tid] += x;
        __syncthreads();
    }
    if (i < N_NODES) {
        int excl = smem[tid] - t + boff[blockIdx.x];
        rp[i] = excl;
        if (i == N_NODES - 1) rp[N_NODES] = excl + t;
        int acc = excl;
        double deg = 1.0;   // self-loop
#pragma unroll
        for (int s = 0; s < 4; s++) {
            unsigned long long p = packed[s * NPAD + i];
            sb[s * NPAD + i] = acc;
            acc += (int)(p >> 48);
            deg += (double)(p & FIX_MASK) * (1.0 / FIX_SCALE);
        }
        dinv[i] = rsqrtf((float)deg);
    }
}

// atomic-free fill: slot = sb[shard][dst] + rank
__global__ __launch_bounds__(256) void k_fill(const int* __restrict__ src,
                                              const int* __restrict__ dst,
                                              const float* __restrict__ ew,
                                              const float* __restrict__ dinv,
                                              const int* __restrict__ sb,
                                              const int* __restrict__ rank,
                                              int2* __restrict__ csr) {
    int e = blockIdx.x * 256 + threadIdx.x;
    int shard = blockIdx.x & 3;
    if (e < N_EDGES) {
        int s = src[e], d = dst[e];
        int slot = sb[shard * NPAD + d] + rank[e];
        float w = dinv[s] * ew[e] * dinv[d];
        csr[slot] = make_int2(s, __builtin_bit_cast(int, w));
    }
}

// ---------- fp32 -> bf16 conversions ----------
__global__ __launch_bounds__(256) void k_cvt2(const float* __restrict__ x, const float* __restrict__ h,
                                              short* __restrict__ xb, short* __restrict__ hb) {
    const int NH4 = (N_NODES * HID) / 4;
    int i = blockIdx.x * 256 + threadIdx.x;
    const float* s; short* d; int idx;
    if (i < NH4) { s = x; d = xb; idx = i; } else { s = h; d = hb; idx = i - NH4; }
    float4 v = ((const float4*)s)[idx];
    short4 o;
    o.x = f2bf(v.x); o.y = f2bf(v.y); o.z = f2bf(v.z); o.w = f2bf(v.w);
    ((short4*)d)[idx] = o;
}

// transpose + convert the 5 weights: WT[n][k] = bf16(W[k][n])
__global__ __launch_bounds__(256) void k_wcvt(const float* __restrict__ W1, const float* __restrict__ W2,
                                              const float* __restrict__ Wu, const float* __restrict__ Wr,
                                              const float* __restrict__ Wc,
                                              short* WT1, short* WT2, short* WTu, short* WTr, short* WTc) {
    int i = blockIdx.x * 256 + threadIdx.x;   // 0..131071
    if (i < 32768) {
        const float* W = (i < 16384) ? W1 : W2;
        short* T = (i < 16384) ? WT1 : WT2;
        int j = i & 16383;
        int n = j >> 7, k = j & 127;
        T[n * 128 + k] = f2bf(W[k * 128 + n]);
    } else {
        int j = i - 32768;
        const float* W = Wu; short* T = WTu;
        if (j >= 65536)      { W = Wc; T = WTc; j -= 65536; }
        else if (j >= 32768) { W = Wr; T = WTr; j -= 32768; }
        int n = j >> 8, k = j & 255;
        T[n * 256 + k] = f2bf(W[k * 128 + n]);
    }
}

// ---------- MFMA GEMM: 16 rows/block (1250 blocks), waves split output cols ----------
__global__ __launch_bounds__(256) void k_gemm_mfma(const short* __restrict__ Ab,
                                                   const short* __restrict__ WT,
                                                   short* __restrict__ Cb) {
    __shared__ short As[16 * 136];
    int tid = threadIdx.x;
    int r0 = blockIdx.x * 16;
    {
        int row = tid >> 4;
        int col0 = (tid & 15) * 8;
        *(bf16x8*)(&As[row * 136 + col0]) = *(const bf16x8*)(Ab + (size_t)(r0 + row) * HID + col0);
    }
    __syncthreads();
    int wave = tid >> 6, lane = tid & 63;
    int m = lane & 15, quad = lane >> 4;
    f32x4 acc[2];
    acc[0] = (f32x4){0.f, 0.f, 0.f, 0.f};
    acc[1] = acc[0];
#pragma unroll
    for (int ks = 0; ks < 4; ks++) {
        int k0 = ks * 32 + quad * 8;
        bf16x8 a = *(const bf16x8*)(&As[m * 136 + k0]);
#pragma unroll
        for (int j = 0; j < 2; j++) {
            int n = (wave * 2 + j) * 16 + m;
            bf16x8 b = *(const bf16x8*)(WT + n * 128 + k0);
            acc[j] = __builtin_amdgcn_mfma_f32_16x16x32_bf16(a, b, acc[j], 0, 0, 0);
        }
    }
#pragma unroll
    for (int j = 0; j < 2; j++) {
        int col = (wave * 2 + j) * 16 + m;
#pragma unroll
        for (int rg = 0; rg < 4; rg++) {
            int grow = r0 + quad * 4 + rg;
            Cb[(size_t)grow * HID + col] = f2bf(acc[j][rg]);
        }
    }
}

// ---------- gather aggregation: one wave per dst node, half-wave per edge pair ----------
__global__ __launch_bounds__(256) void k_aggregate(const short* __restrict__ xw,
                                                   short* __restrict__ outb,
                                                   const int* __restrict__ rp,
                                                   const int2* __restrict__ csr,
                                                   const float* __restrict__ dinv,
                                                   const float* __restrict__ bias,
                                                   int act) {
    int node = blockIdx.x * 4 + (threadIdx.x >> 6);
    int lane = threadIdx.x & 63;
    int half = lane >> 5;
    int l = lane & 31;
    float4 acc = {0.f, 0.f, 0.f, 0.f};
    if (half == 0) {   // self-loop term, counted once
        float dv = dinv[node];
        float dv2 = dv * dv;
        float4 v = unpack_bf4(((const uint2*)(xw + (size_t)node * HID))[l]);
        acc.x = v.x * dv2; acc.y = v.y * dv2; acc.z = v.z * dv2; acc.w = v.w * dv2;
    }
    int j = rp[node], end = rp[node + 1];
    for (; j + 7 < end; j += 8) {
        int2 e0 = csr[j + 0 + half];
        int2 e1 = csr[j + 2 + half];
        int2 e2 = csr[j + 4 + half];
        int2 e3 = csr[j + 6 + half];
        float4 v0 = unpack_bf4(((const uint2*)(xw + (size_t)e0.x * HID))[l]);
        float4 v1 = unpack_bf4(((const uint2*)(xw + (size_t)e1.x * HID))[l]);
        float4 v2 = unpack_bf4(((const uint2*)(xw + (size_t)e2.x * HID))[l]);
        float4 v3 = unpack_bf4(((const uint2*)(xw + (size_t)e3.x * HID))[l]);
        float w0 = __builtin_bit_cast(float, e0.y);
        float w1 = __builtin_bit_cast(float, e1.y);
        float w2 = __builtin_bit_cast(float, e2.y);
        float w3 = __builtin_bit_cast(float, e3.y);
        acc.x += v0.x * w0; acc.y += v0.y * w0; acc.z += v0.z * w0; acc.w += v0.w * w0;
        acc.x += v1.x * w1; acc.y += v1.y * w1; acc.z += v1.z * w1; acc.w += v1.w * w1;
        acc.x += v2.x * w2; acc.y += v2.y * w2; acc.z += v2.z * w2; acc.w += v2.w * w2;
        acc.x += v3.x * w3; acc.y += v3.y * w3; acc.z += v3.z * w3; acc.w += v3.w * w3;
    }
    for (; j + 1 < end; j += 2) {
        int2 e0 = csr[j + half];
        float4 v0 = unpack_bf4(((const uint2*)(xw + (size_t)e0.x * HID))[l]);
        float w0 = __builtin_bit_cast(float, e0.y);
        acc.x += v0.x * w0; acc.y += v0.y * w0; acc.z += v0.z * w0; acc.w += v0.w * w0;
    }
    if (j < end && half == 0) {
        int2 e0 = csr[j];
        float4 v0 = unpack_bf4(((const uint2*)(xw + (size_t)e0.x * HID))[l]);
        float w0 = __builtin_bit_cast(float, e0.y);
        acc.x += v0.x * w0; acc.y += v0.y * w0; acc.z += v0.z * w0; acc.w += v0.w * w0;
    }
    acc.x += __shfl_xor(acc.x, 32);
    acc.y += __shfl_xor(acc.y, 32);
    acc.z += __shfl_xor(acc.z, 32);
    acc.w += __shfl_xor(acc.w, 32);
    if (half == 0) {
        float4 b = ((const float4*)bias)[l];
        acc.x += b.x; acc.y += b.y; acc.z += b.z; acc.w += b.w;
        if (act == 0) {
            acc.x = fmaxf(acc.x, 0.f); acc.y = fmaxf(acc.y, 0.f);
            acc.z = fmaxf(acc.z, 0.f); acc.w = fmaxf(acc.w, 0.f);
        } else {
            acc.x = 1.f / (1.f + __expf(-acc.x)); acc.y = 1.f / (1.f + __expf(-acc.y));
            acc.z = 1.f / (1.f + __expf(-acc.z)); acc.w = 1.f / (1.f + __expf(-acc.w));
        }
        ((uint2*)(outb + (size_t)node * HID))[l] = pack_bf4(acc);
    }
}

// ---------- fused gate: 16 rows/block (1250 blocks), waves split output cols ----------
__global__ __launch_bounds__(256) void k_gate(const short* __restrict__ xgb, const short* __restrict__ hb,
                                              const float* __restrict__ hf,
                                              const short* __restrict__ WTu, const short* __restrict__ WTr,
                                              const short* __restrict__ WTc,
                                              const float* __restrict__ pbu, const float* __restrict__ pbr,
                                              const float* __restrict__ pbc,
                                              float* __restrict__ out) {
    __shared__ short Xs[16 * 264];   // [row][0:128]=xg, [128:256]=h (later r*h)
    int tid = threadIdx.x;
    int r0 = blockIdx.x * 16;
#pragma unroll
    for (int i = 0; i < 2; i++) {
        int c = tid + i * 256;
        int row = c >> 5;
        int col0 = (c & 31) * 8;
        int grow = r0 + row;
        bf16x8 v;
        if (col0 < 128) v = *(const bf16x8*)(xgb + (size_t)grow * HID + col0);
        else            v = *(const bf16x8*)(hb + (size_t)grow * HID + (col0 - 128));
        *(bf16x8*)(&Xs[row * 264 + col0]) = v;
    }
    __syncthreads();
    int wave = tid >> 6, lane = tid & 63;
    int m = lane & 15, quad = lane >> 4;
    f32x4 au[2], ar[2];
    au[0] = (f32x4){0.f, 0.f, 0.f, 0.f};
    au[1] = au[0]; ar[0] = au[0]; ar[1] = au[0];
#pragma unroll
    for (int ks = 0; ks < 8; ks++) {
        int k0 = ks * 32 + quad * 8;
        bf16x8 a = *(const bf16x8*)(&Xs[m * 264 + k0]);
#pragma unroll
        for (int j = 0; j < 2; j++) {
            int n = (wave * 2 + j) * 16 + m;
            bf16x8 bu_f = *(const bf16x8*)(WTu + n * 256 + k0);
            au[j] = __builtin_amdgcn_mfma_f32_16x16x32_bf16(a, bu_f, au[j], 0, 0, 0);
            bf16x8 br_f = *(const bf16x8*)(WTr + n * 256 + k0);
            ar[j] = __builtin_amdgcn_mfma_f32_16x16x32_bf16(a, br_f, ar[j], 0, 0, 0);
        }
    }
    __syncthreads();   // phase-1 reads of the h half must finish before overwrite
#pragma unroll
    for (int j = 0; j < 2; j++) {
        int col = (wave * 2 + j) * 16 + m;
        float brv = pbr[col];
#pragma unroll
        for (int rg = 0; rg < 4; rg++) {
            int trow = quad * 4 + rg;
            float rv = 1.f / (1.f + __expf(-(ar[j][rg] + brv)));
            float hv = bf2f(Xs[trow * 264 + 128 + col]);
            Xs[trow * 264 + 128 + col] = f2bf(rv * hv);
        }
    }
    __syncthreads();
    f32x4 ac[2];
    ac[0] = (f32x4){0.f, 0.f, 0.f, 0.f};
    ac[1] = ac[0];
#pragma unroll
    for (int ks = 0; ks < 8; ks++) {
        int k0 = ks * 32 + quad * 8;
        bf16x8 a = *(const bf16x8*)(&Xs[m * 264 + k0]);
#pragma unroll
        for (int j = 0; j < 2; j++) {
            int n = (wave * 2 + j) * 16 + m;
            bf16x8 bc_f = *(const bf16x8*)(WTc + n * 256 + k0);
            ac[j] = __builtin_amdgcn_mfma_f32_16x16x32_bf16(a, bc_f, ac[j], 0, 0, 0);
        }
    }
#pragma unroll
    for (int j = 0; j < 2; j++) {
        int col = (wave * 2 + j) * 16 + m;
        float buv = pbu[col], bcv = pbc[col];
#pragma unroll
        for (int rg = 0; rg < 4; rg++) {
            int grow = r0 + quad * 4 + rg;
            float uv = 1.f / (1.f + __expf(-(au[j][rg] + buv)));
            float cv = tanhf(ac[j][rg] + bcv);
            float hv = hf[(size_t)grow * HID + col];
            out[(size_t)grow * HID + col] = uv * hv + (1.f - uv) * cv;
        }
    }
}

extern "C" void kernel_launch(void* const* d_in, const int* in_sizes, int n_in,
                              void* d_out, int out_size, void* d_ws, size_t ws_size,
                              hipStream_t stream) {
    const float* x  = (const float*)d_in[0];
    const int*   ei = (const int*)d_in[1];
    const float* ew = (const float*)d_in[2];
    const float* h  = (const float*)d_in[3];
    const float* W1 = (const float*)d_in[4];
    const float* b1 = (const float*)d_in[5];
    const float* W2 = (const float*)d_in[6];
    const float* b2 = (const float*)d_in[7];
    const float* Wu = (const float*)d_in[8];
    const float* bu = (const float*)d_in[9];
    const float* Wr = (const float*)d_in[10];
    const float* br = (const float*)d_in[11];
    const float* Wc = (const float*)d_in[12];
    const float* bc = (const float*)d_in[13];
    const int* src = ei;
    const int* dst = ei + N_EDGES;
    float* out = (float*)d_out;

    const size_t NH = (size_t)N_NODES * HID;
    float* ws = (float*)d_ws;
    float* dinv = ws;                                          // NPAD f32
    int*   rp   = (int*)(ws + NPAD);                           // NPAD
    unsigned long long* packed = (unsigned long long*)(ws + 2 * NPAD);  // 4*NPAD u64
    int*   sb   = (int*)(ws + 10 * NPAD);                      // 4*NPAD
    int*   tot  = (int*)(ws + 14 * NPAD);                      // NPAD
    int*   bsum = (int*)(ws + 15 * NPAD);                      // 128
    int*   boff = (int*)(ws + 15 * NPAD + 128);                // 128
    int*   rank = (int*)(ws + 15 * NPAD + 256);                // N_EDGES
    int2*  csr  = (int2*)(ws + 15 * NPAD + 256 + N_EDGES);     // N_EDGES int2
    short* xb  = (short*)(ws + 15 * NPAD + 256 + 3 * N_EDGES);
    short* hb  = xb + NH;
    short* xw  = hb + NH;
    short* h1b = xw + NH;
    short* xgb = h1b + NH;
    short* WT1 = xgb + NH;
    short* WT2 = WT1 + 16384;
    short* WTu = WT2 + 16384;
    short* WTr = WTu + 32768;
    short* WTc = WTr + 32768;

    // CSR + normalization
    k_init<<<(4 * NPAD + 255) / 256, 256, 0, stream>>>(packed);
    k_hist<<<N_EDGES / 256, 256, 0, stream>>>(packed, rank, dst, ew);
    k_scan_part<<<NBLK, 256, 0, stream>>>(packed, tot, bsum);
    k_scan_bsum<<<1, 128, 0, stream>>>(bsum, boff);
    k_scan_final<<<NBLK, 256, 0, stream>>>(packed, tot, boff, rp, sb, dinv);
    k_fill<<<N_EDGES / 256, 256, 0, stream>>>(src, dst, ew, dinv, sb, rank, csr);

    // bf16 conversions
    k_cvt2<<<(int)(2 * NH / 1024), 256, 0, stream>>>(x, h, xb, hb);
    k_wcvt<<<512, 256, 0, stream>>>(W1, W2, Wu, Wr, Wc, WT1, WT2, WTu, WTr, WTc);

    // layer 1
    k_gemm_mfma<<<N_NODES / 16, 256, 0, stream>>>(xb, WT1, xw);
    k_aggregate<<<N_NODES / 4, 256, 0, stream>>>(xw, h1b, rp, csr, dinv, b1, 0);
    // layer 2
    k_gemm_mfma<<<N_NODES / 16, 256, 0, stream>>>(h1b, WT2, xw);
    k_aggregate<<<N_NODES / 4, 256, 0, stream>>>(xw, xgb, rp, csr, dinv, b2, 1);
    // fused gating
    k_gate<<<N_NODES / 16, 256, 0, stream>>>(xgb, hb, h, WTu, WTr, WTc, bu, br, bc, out);
}

// Round 7
// 252.142 us; speedup vs baseline: 1.5223x; 1.0224x over previous
//
#include <hip/hip_runtime.h>
#include <math.h>

#define N_NODES 20000
#define N_EDGES 640000
#define HID 128
#define NPAD 20224
#define NBLK 79      // ceil(N_NODES/256)
#define NSHARD 8

typedef __attribute__((ext_vector_type(8))) short bf16x8;
typedef __attribute__((ext_vector_type(4))) float f32x4;

#define FIX_SCALE 274877906944.0   // 2^38
#define FIX_MASK ((1ull << 48) - 1)

__device__ inline short f2bf(float f) {
    unsigned u = __builtin_bit_cast(unsigned, f);
    u += 0x7fffu + ((u >> 16) & 1u);      // RNE
    return (short)(u >> 16);
}
__device__ inline float bf2f(short s) {
    unsigned u = ((unsigned)(unsigned short)s) << 16;
    return __builtin_bit_cast(float, u);
}
__device__ inline float4 unpack_bf4(uint2 v) {
    float4 f;
    f.x = __builtin_bit_cast(float, v.x << 16);
    f.y = __builtin_bit_cast(float, v.x & 0xffff0000u);
    f.z = __builtin_bit_cast(float, v.y << 16);
    f.w = __builtin_bit_cast(float, v.y & 0xffff0000u);
    return f;
}
__device__ inline uint2 pack_bf4(float4 f) {
    uint2 v;
    v.x = (unsigned)(unsigned short)f2bf(f.x) | ((unsigned)(unsigned short)f2bf(f.y) << 16);
    v.y = (unsigned)(unsigned short)f2bf(f.z) | ((unsigned)(unsigned short)f2bf(f.w) << 16);
    return v;
}
__device__ inline bf16x8 cvt8(float4 a0, float4 a1) {
    bf16x8 v;
    v[0] = f2bf(a0.x); v[1] = f2bf(a0.y); v[2] = f2bf(a0.z); v[3] = f2bf(a0.w);
    v[4] = f2bf(a1.x); v[5] = f2bf(a1.y); v[6] = f2bf(a1.z); v[7] = f2bf(a1.w);
    return v;
}

// ---------- CSR build (8-sharded histogram) ----------
__global__ __launch_bounds__(256) void k_init(unsigned long long* packed) {
    int i = blockIdx.x * 256 + threadIdx.x;
    if (i < NSHARD * NPAD) packed[i] = 0ull;
}

// one u64 atomic per edge into shard (blockIdx&7): count [63:48], fixed-point deg [47:0]
__global__ __launch_bounds__(256) void k_hist(unsigned long long* packed, int* __restrict__ rank,
                                              const int* __restrict__ dst,
                                              const float* __restrict__ ew) {
    int e = blockIdx.x * 256 + threadIdx.x;
    int shard = blockIdx.x & (NSHARD - 1);
    if (e < N_EDGES) {
        int d = dst[e];
        unsigned long long add = (1ull << 48) | (unsigned long long)((double)ew[e] * FIX_SCALE);
        unsigned long long old = atomicAdd(&packed[shard * NPAD + d], add);
        rank[e] = (int)(old >> 48);
    }
}

// ---------- scan phase 1: per-node totals + per-block sums ----------
__global__ __launch_bounds__(256) void k_scan_part(const unsigned long long* __restrict__ packed,
                                                   int* __restrict__ tot, int* __restrict__ bsum) {
    __shared__ int red[256];
    int tid = threadIdx.x;
    int i = blockIdx.x * 256 + tid;
    int t = 0;
    if (i < N_NODES) {
#pragma unroll
        for (int s = 0; s < NSHARD; s++) t += (int)(packed[s * NPAD + i] >> 48);
        tot[i] = t;
    }
    red[tid] = t;
    __syncthreads();
    for (int off = 128; off > 0; off >>= 1) {
        if (tid < off) red[tid] += red[tid + off];
        __syncthreads();
    }
    if (tid == 0) bsum[blockIdx.x] = red[0];
}

// ---------- scan phase 2 (fused): block offset from bsum + in-block scan -> rp, sb, dinv ----------
__global__ __launch_bounds__(256) void k_scan_final(const unsigned long long* __restrict__ packed,
                                                    const int* __restrict__ tot,
                                                    const int* __restrict__ bsum,
                                                    int* __restrict__ rp, int* __restrict__ sb,
                                                    float* __restrict__ dinv) {
    __shared__ int smem[256];
    __shared__ int red[256];
    int tid = threadIdx.x;
    red[tid] = (tid < blockIdx.x) ? bsum[tid] : 0;   // blockIdx.x <= 78 < 256
    int i = blockIdx.x * 256 + tid;
    int t = (i < N_NODES) ? tot[i] : 0;
    smem[tid] = t;
    __syncthreads();
    for (int off = 128; off > 0; off >>= 1) {
        if (tid < off) red[tid] += red[tid + off];
        __syncthreads();
    }
    for (int off = 1; off < 256; off <<= 1) {
        int x = (tid >= off) ? smem[tid - off] : 0;
        __syncthreads();
        smem[tid] += x;
        __syncthreads();
    }
    if (i < N_NODES) {
        int excl = smem[tid] - t + red[0];
        rp[i] = excl;
        if (i == N_NODES - 1) rp[N_NODES] = excl + t;
        int acc = excl;
        double deg = 1.0;   // self-loop
#pragma unroll
        for (int s = 0; s < NSHARD; s++) {
            unsigned long long p = packed[s * NPAD + i];
            sb[s * NPAD + i] = acc;
            acc += (int)(p >> 48);
            deg += (double)(p & FIX_MASK) * (1.0 / FIX_SCALE);
        }
        dinv[i] = rsqrtf((float)deg);
    }
}

// atomic-free fill: slot = sb[shard][dst] + rank
__global__ __launch_bounds__(256) void k_fill(const int* __restrict__ src,
                                              const int* __restrict__ dst,
                                              const float* __restrict__ ew,
                                              const float* __restrict__ dinv,
                                              const int* __restrict__ sb,
                                              const int* __restrict__ rank,
                                              int2* __restrict__ csr) {
    int e = blockIdx.x * 256 + threadIdx.x;
    int shard = blockIdx.x & (NSHARD - 1);
    if (e < N_EDGES) {
        int s = src[e], d = dst[e];
        int slot = sb[shard * NPAD + d] + rank[e];
        float w = dinv[s] * ew[e] * dinv[d];
        csr[slot] = make_int2(s, __builtin_bit_cast(int, w));
    }
}

// transpose + convert the 5 weights: WT[n][k] = bf16(W[k][n])
__global__ __launch_bounds__(256) void k_wcvt(const float* __restrict__ W1, const float* __restrict__ W2,
                                              const float* __restrict__ Wu, const float* __restrict__ Wr,
                                              const float* __restrict__ Wc,
                                              short* WT1, short* WT2, short* WTu, short* WTr, short* WTc) {
    int i = blockIdx.x * 256 + threadIdx.x;   // 0..131071
    if (i < 32768) {
        const float* W = (i < 16384) ? W1 : W2;
        short* T = (i < 16384) ? WT1 : WT2;
        int j = i & 16383;
        int n = j >> 7, k = j & 127;
        T[n * 128 + k] = f2bf(W[k * 128 + n]);
    } else {
        int j = i - 32768;
        const float* W = Wu; short* T = WTu;
        if (j >= 65536)      { W = Wc; T = WTc; j -= 65536; }
        else if (j >= 32768) { W = Wr; T = WTr; j -= 32768; }
        int n = j >> 8, k = j & 255;
        T[n * 256 + k] = f2bf(W[k * 128 + n]);
    }
}

// ---------- MFMA GEMM: 16 rows/block; A either fp32 (inline convert) or bf16 ----------
__global__ __launch_bounds__(256) void k_gemm_mfma(const float* __restrict__ Af,
                                                   const short* __restrict__ Ab,
                                                   const short* __restrict__ WT,
                                                   short* __restrict__ Cb) {
    __shared__ short As[16 * 136];
    int tid = threadIdx.x;
    int r0 = blockIdx.x * 16;
    {
        int row = tid >> 4;
        int col0 = (tid & 15) * 8;
        bf16x8 v;
        if (Af) {
            const float* p = Af + (size_t)(r0 + row) * HID + col0;
            v = cvt8(*(const float4*)p, *(const float4*)(p + 4));
        } else {
            v = *(const bf16x8*)(Ab + (size_t)(r0 + row) * HID + col0);
        }
        *(bf16x8*)(&As[row * 136 + col0]) = v;
    }
    __syncthreads();
    int wave = tid >> 6, lane = tid & 63;
    int m = lane & 15, quad = lane >> 4;
    f32x4 acc[2];
    acc[0] = (f32x4){0.f, 0.f, 0.f, 0.f};
    acc[1] = acc[0];
#pragma unroll
    for (int ks = 0; ks < 4; ks++) {
        int k0 = ks * 32 + quad * 8;
        bf16x8 a = *(const bf16x8*)(&As[m * 136 + k0]);
#pragma unroll
        for (int j = 0; j < 2; j++) {
            int n = (wave * 2 + j) * 16 + m;
            bf16x8 b = *(const bf16x8*)(WT + n * 128 + k0);
            acc[j] = __builtin_amdgcn_mfma_f32_16x16x32_bf16(a, b, acc[j], 0, 0, 0);
        }
    }
#pragma unroll
    for (int j = 0; j < 2; j++) {
        int col = (wave * 2 + j) * 16 + m;
#pragma unroll
        for (int rg = 0; rg < 4; rg++) {
            int grow = r0 + quad * 4 + rg;
            Cb[(size_t)grow * HID + col] = f2bf(acc[j][rg]);
        }
    }
}

// ---------- gather aggregation: one wave per dst node, half-wave per edge ----------
__global__ __launch_bounds__(256) void k_aggregate(const short* __restrict__ xw,
                                                   short* __restrict__ outb,
                                                   const int* __restrict__ rp,
                                                   const int2* __restrict__ csr,
                                                   const float* __restrict__ dinv,
                                                   const float* __restrict__ bias,
                                                   int act) {
    int node = blockIdx.x * 4 + (threadIdx.x >> 6);
    int lane = threadIdx.x & 63;
    int half = lane >> 5;
    int l = lane & 31;
    float4 acc = {0.f, 0.f, 0.f, 0.f};
    if (half == 0) {   // self-loop term, counted once
        float dv = dinv[node];
        float dv2 = dv * dv;
        float4 v = unpack_bf4(((const uint2*)(xw + (size_t)node * HID))[l]);
        acc.x = v.x * dv2; acc.y = v.y * dv2; acc.z = v.z * dv2; acc.w = v.w * dv2;
    }
    int j = rp[node], end = rp[node + 1];
    for (; j + 15 < end; j += 16) {          // 16 edges/iter: 8 row-gathers in flight per half
        int2 e[8];
#pragma unroll
        for (int i = 0; i < 8; i++) e[i] = csr[j + 2 * i + half];
        float4 v[8];
#pragma unroll
        for (int i = 0; i < 8; i++) v[i] = unpack_bf4(((const uint2*)(xw + (size_t)e[i].x * HID))[l]);
#pragma unroll
        for (int i = 0; i < 8; i++) {
            float w = __builtin_bit_cast(float, e[i].y);
            acc.x += v[i].x * w; acc.y += v[i].y * w; acc.z += v[i].z * w; acc.w += v[i].w * w;
        }
    }
    for (; j + 7 < end; j += 8) {
        int2 e[4];
#pragma unroll
        for (int i = 0; i < 4; i++) e[i] = csr[j + 2 * i + half];
        float4 v[4];
#pragma unroll
        for (int i = 0; i < 4; i++) v[i] = unpack_bf4(((const uint2*)(xw + (size_t)e[i].x * HID))[l]);
#pragma unroll
        for (int i = 0; i < 4; i++) {
            float w = __builtin_bit_cast(float, e[i].y);
            acc.x += v[i].x * w; acc.y += v[i].y * w; acc.z += v[i].z * w; acc.w += v[i].w * w;
        }
    }
    for (; j + 1 < end; j += 2) {
        int2 e0 = csr[j + half];
        float4 v0 = unpack_bf4(((const uint2*)(xw + (size_t)e0.x * HID))[l]);
        float w0 = __builtin_bit_cast(float, e0.y);
        acc.x += v0.x * w0; acc.y += v0.y * w0; acc.z += v0.z * w0; acc.w += v0.w * w0;
    }
    if (j < end && half == 0) {
        int2 e0 = csr[j];
        float4 v0 = unpack_bf4(((const uint2*)(xw + (size_t)e0.x * HID))[l]);
        float w0 = __builtin_bit_cast(float, e0.y);
        acc.x += v0.x * w0; acc.y += v0.y * w0; acc.z += v0.z * w0; acc.w += v0.w * w0;
    }
    acc.x += __shfl_xor(acc.x, 32);
    acc.y += __shfl_xor(acc.y, 32);
    acc.z += __shfl_xor(acc.z, 32);
    acc.w += __shfl_xor(acc.w, 32);
    if (half == 0) {
        float4 b = ((const float4*)bias)[l];
        acc.x += b.x; acc.y += b.y; acc.z += b.z; acc.w += b.w;
        if (act == 0) {
            acc.x = fmaxf(acc.x, 0.f); acc.y = fmaxf(acc.y, 0.f);
            acc.z = fmaxf(acc.z, 0.f); acc.w = fmaxf(acc.w, 0.f);
        } else {
            acc.x = 1.f / (1.f + __expf(-acc.x)); acc.y = 1.f / (1.f + __expf(-acc.y));
            acc.z = 1.f / (1.f + __expf(-acc.z)); acc.w = 1.f / (1.f + __expf(-acc.w));
        }
        ((uint2*)(outb + (size_t)node * HID))[l] = pack_bf4(acc);
    }
}

// ---------- fused gate: 16 rows/block, h staged from fp32 inline ----------
__global__ __launch_bounds__(256) void k_gate(const short* __restrict__ xgb,
                                              const float* __restrict__ hf,
                                              const short* __restrict__ WTu, const short* __restrict__ WTr,
                                              const short* __restrict__ WTc,
                                              const float* __restrict__ pbu, const float* __restrict__ pbr,
                                              const float* __restrict__ pbc,
                                              float* __restrict__ out) {
    __shared__ short Xs[16 * 264];   // [row][0:128]=xg, [128:256]=h (later r*h)
    int tid = threadIdx.x;
    int r0 = blockIdx.x * 16;
#pragma unroll
    for (int i = 0; i < 2; i++) {
        int c = tid + i * 256;
        int row = c >> 5;
        int col0 = (c & 31) * 8;
        int grow = r0 + row;
        bf16x8 v;
        if (col0 < 128) {
            v = *(const bf16x8*)(xgb + (size_t)grow * HID + col0);
        } else {
            const float* p = hf + (size_t)grow * HID + (col0 - 128);
            v = cvt8(*(const float4*)p, *(const float4*)(p + 4));
        }
        *(bf16x8*)(&Xs[row * 264 + col0]) = v;
    }
    __syncthreads();
    int wave = tid >> 6, lane = tid & 63;
    int m = lane & 15, quad = lane >> 4;
    f32x4 au[2], ar[2];
    au[0] = (f32x4){0.f, 0.f, 0.f, 0.f};
    au[1] = au[0]; ar[0] = au[0]; ar[1] = au[0];
#pragma unroll
    for (int ks = 0; ks < 8; ks++) {
        int k0 = ks * 32 + quad * 8;
        bf16x8 a = *(const bf16x8*)(&Xs[m * 264 + k0]);
#pragma unroll
        for (int j = 0; j < 2; j++) {
            int n = (wave * 2 + j) * 16 + m;
            bf16x8 bu_f = *(const bf16x8*)(WTu + n * 256 + k0);
            au[j] = __builtin_amdgcn_mfma_f32_16x16x32_bf16(a, bu_f, au[j], 0, 0, 0);
            bf16x8 br_f = *(const bf16x8*)(WTr + n * 256 + k0);
            ar[j] = __builtin_amdgcn_mfma_f32_16x16x32_bf16(a, br_f, ar[j], 0, 0, 0);
        }
    }
    __syncthreads();   // phase-1 reads of the h half must finish before overwrite
#pragma unroll
    for (int j = 0; j < 2; j++) {
        int col = (wave * 2 + j) * 16 + m;
        float brv = pbr[col];
#pragma unroll
        for (int rg = 0; rg < 4; rg++) {
            int trow = quad * 4 + rg;
            float rv = 1.f / (1.f + __expf(-(ar[j][rg] + brv)));
            float hv = bf2f(Xs[trow * 264 + 128 + col]);
            Xs[trow * 264 + 128 + col] = f2bf(rv * hv);
        }
    }
    __syncthreads();
    f32x4 ac[2];
    ac[0] = (f32x4){0.f, 0.f, 0.f, 0.f};
    ac[1] = ac[0];
#pragma unroll
    for (int ks = 0; ks < 8; ks++) {
        int k0 = ks * 32 + quad * 8;
        bf16x8 a = *(const bf16x8*)(&Xs[m * 264 + k0]);
#pragma unroll
        for (int j = 0; j < 2; j++) {
            int n = (wave * 2 + j) * 16 + m;
            bf16x8 bc_f = *(const bf16x8*)(WTc + n * 256 + k0);
            ac[j] = __builtin_amdgcn_mfma_f32_16x16x32_bf16(a, bc_f, ac[j], 0, 0, 0);
        }
    }
#pragma unroll
    for (int j = 0; j < 2; j++) {
        int col = (wave * 2 + j) * 16 + m;
        float buv = pbu[col], bcv = pbc[col];
#pragma unroll
        for (int rg = 0; rg < 4; rg++) {
            int grow = r0 + quad * 4 + rg;
            float uv = 1.f / (1.f + __expf(-(au[j][rg] + buv)));
            float cv = tanhf(ac[j][rg] + bcv);
            float hv = hf[(size_t)grow * HID + col];
            out[(size_t)grow * HID + col] = uv * hv + (1.f - uv) * cv;
        }
    }
}

extern "C" void kernel_launch(void* const* d_in, const int* in_sizes, int n_in,
                              void* d_out, int out_size, void* d_ws, size_t ws_size,
                              hipStream_t stream) {
    const float* x  = (const float*)d_in[0];
    const int*   ei = (const int*)d_in[1];
    const float* ew = (const float*)d_in[2];
    const float* h  = (const float*)d_in[3];
    const float* W1 = (const float*)d_in[4];
    const float* b1 = (const float*)d_in[5];
    const float* W2 = (const float*)d_in[6];
    const float* b2 = (const float*)d_in[7];
    const float* Wu = (const float*)d_in[8];
    const float* bu = (const float*)d_in[9];
    const float* Wr = (const float*)d_in[10];
    const float* br = (const float*)d_in[11];
    const float* Wc = (const float*)d_in[12];
    const float* bc = (const float*)d_in[13];
    const int* src = ei;
    const int* dst = ei + N_EDGES;
    float* out = (float*)d_out;

    const size_t NH = (size_t)N_NODES * HID;
    float* ws = (float*)d_ws;
    float* dinv = ws;                                            // NPAD f32
    int*   rp   = (int*)(ws + NPAD);                             // NPAD
    unsigned long long* packed = (unsigned long long*)(ws + 2 * NPAD);  // 8*NPAD u64 = 16*NPAD f32
    int*   sb   = (int*)(ws + 18 * NPAD);                        // 8*NPAD
    int*   tot  = (int*)(ws + 26 * NPAD);                        // NPAD
    int*   bsum = (int*)(ws + 27 * NPAD);                        // 128
    int*   rank = (int*)(ws + 27 * NPAD + 128);                  // N_EDGES
    int2*  csr  = (int2*)(ws + 27 * NPAD + 128 + N_EDGES);       // N_EDGES int2
    short* xw  = (short*)(ws + 27 * NPAD + 128 + 3 * N_EDGES);   // NH bf16 (reused both layers)
    short* h1b = xw + NH;
    short* xgb = h1b + NH;
    short* WT1 = xgb + NH;
    short* WT2 = WT1 + 16384;
    short* WTu = WT2 + 16384;
    short* WTr = WTu + 32768;
    short* WTc = WTr + 32768;

    // CSR + normalization
    k_init<<<(NSHARD * NPAD + 255) / 256, 256, 0, stream>>>(packed);
    k_hist<<<N_EDGES / 256, 256, 0, stream>>>(packed, rank, dst, ew);
    k_scan_part<<<NBLK, 256, 0, stream>>>(packed, tot, bsum);
    k_scan_final<<<NBLK, 256, 0, stream>>>(packed, tot, bsum, rp, sb, dinv);
    k_fill<<<N_EDGES / 256, 256, 0, stream>>>(src, dst, ew, dinv, sb, rank, csr);

    // weights to bf16 (transposed)
    k_wcvt<<<512, 256, 0, stream>>>(W1, W2, Wu, Wr, Wc, WT1, WT2, WTu, WTr, WTc);

    // layer 1 (x converted inline in gemm staging)
    k_gemm_mfma<<<N_NODES / 16, 256, 0, stream>>>(x, nullptr, WT1, xw);
    k_aggregate<<<N_NODES / 4, 256, 0, stream>>>(xw, h1b, rp, csr, dinv, b1, 0);
    // layer 2
    k_gemm_mfma<<<N_NODES / 16, 256, 0, stream>>>(nullptr, h1b, WT2, xw);
    k_aggregate<<<N_NODES / 4, 256, 0, stream>>>(xw, xgb, rp, csr, dinv, b2, 1);
    // fused gating (h converted inline in staging)
    k_gate<<<N_NODES / 16, 256, 0, stream>>>(xgb, h, WTu, WTr, WTc, bu, br, bc, out);
}